// Round 14
// baseline (298.614 us; speedup 1.0000x reference)
//
#include <hip/hip_runtime.h>
#include <hip/hip_bf16.h>

#define H_DIM 1024
#define I_DIM 2048
#define NE 8
#define NT 4096

typedef __bf16 bf16x8 __attribute__((ext_vector_type(8)));
typedef __bf16 bf16x4 __attribute__((ext_vector_type(4)));
typedef float f32x4 __attribute__((ext_vector_type(4)));

// 16B-chunk index within a [rows][8-chunk] LDS tile, XOR-swizzled (verified
// conflict-free R1-R13: SQ_LDS_BANK_CONFLICT == 0).
__device__ __forceinline__ int swzc(int r, int j) { return r * 8 + (j ^ (r & 7)); }

// async global->LDS, 16B per lane. LDS dest is wave-uniform base (HW adds lane*16).
__device__ __forceinline__ void gl16(const void* g, void* l) {
  __builtin_amdgcn_global_load_lds(
      (const __attribute__((address_space(1))) unsigned int*)g,
      (__attribute__((address_space(3))) unsigned int*)l, 16, 0, 0);
}

__device__ __forceinline__ bf16x8 cvt8(float4 a, float4 b) {
  bf16x8 r;
  r[0] = (__bf16)a.x; r[1] = (__bf16)a.y; r[2] = (__bf16)a.z; r[3] = (__bf16)a.w;
  r[4] = (__bf16)b.x; r[5] = (__bf16)b.y; r[6] = (__bf16)b.z; r[7] = (__bf16)b.w;
  return r;
}

__device__ __forceinline__ bf16x8 cvt8v(f32x4 a, f32x4 b) {
  bf16x8 r;
  r[0] = (__bf16)a[0]; r[1] = (__bf16)a[1]; r[2] = (__bf16)a[2]; r[3] = (__bf16)a[3];
  r[4] = (__bf16)b[0]; r[5] = (__bf16)b[1]; r[6] = (__bf16)b[2]; r[7] = (__bf16)b[3];
  return r;
}

// nontemporal fp32->bf16 chunk cast: src read once, dst written once ->
// bypass L2/L3 with nt hints (don't evict data the GEMMs want cached).
__device__ __forceinline__ void castchunk_nt(const float* s, __bf16* d, int off) {
  const f32x4* s4 = (const f32x4*)s;
  f32x4 a = __builtin_nontemporal_load(s4 + (size_t)off * 2);
  f32x4 b = __builtin_nontemporal_load(s4 + (size_t)off * 2 + 1);
  __builtin_nontemporal_store(cvt8v(a, b), (bf16x8*)d + off);
}

#define NBW 16384   // wg+wu cast blocks: 2 * 2^21 chunks / 256
#define NBS 2048    // sg+su cast blocks: 2 * 2^18 chunks / 256

// Prep: cast upgate's weights (wg,wu,sg,su) + router SCORING ONLY (no
// atomics — slot assignment in k_sched's LDS histogram, R13 win).
__global__ __launch_bounds__(256) void k_prep(
    const float* __restrict__ wg, const float* __restrict__ wu,
    const float* __restrict__ sg, const float* __restrict__ su,
    __bf16* __restrict__ wgb, __bf16* __restrict__ wub,
    __bf16* __restrict__ sgb, __bf16* __restrict__ sub,
    const float* __restrict__ x, const float* __restrict__ rw,
    const float* __restrict__ rbias, __bf16* __restrict__ xb,
    int* __restrict__ tE, float* __restrict__ tG) {
  if (blockIdx.x < NBW + NBS) {
    const float* s; __bf16* d; int off;
    if (blockIdx.x < NBW) {
      int i = blockIdx.x * 256 + threadIdx.x;
      if (i < (1 << 21)) { s = wg; d = wgb; off = i; }
      else { s = wu; d = wub; off = i - (1 << 21); }
    } else {
      int i = (blockIdx.x - NBW) * 256 + threadIdx.x;
      if (i < (1 << 18)) { s = sg; d = sgb; off = i; }
      else { s = su; d = sub; off = i - (1 << 18); }
    }
    castchunk_nt(s, d, off);
    return;
  }
  // ---- router scoring (sigmoid top-2 renorm; fuses x->bf16; NO atomics) ----
  int blk = blockIdx.x - (NBW + NBS);         // 0..1023
  int wv = threadIdx.x >> 6, lane = threadIdx.x & 63;
  int t = blk * 4 + wv;
  float acc[NE];
#pragma unroll
  for (int e = 0; e < NE; e++) acc[e] = 0.f;
  const float4* xr = (const float4*)(x + (size_t)t * H_DIM);
  const float4* wr4 = (const float4*)rw;
  bf16x4* xo = (bf16x4*)xb + (size_t)t * (H_DIM / 4);
#pragma unroll
  for (int it = 0; it < 4; ++it) {
    int c = it * 64 + lane;
    float4 xv = xr[c];
    bf16x4 bv;
    bv[0] = (__bf16)xv.x; bv[1] = (__bf16)xv.y;
    bv[2] = (__bf16)xv.z; bv[3] = (__bf16)xv.w;
    xo[c] = bv;
#pragma unroll
    for (int e = 0; e < NE; e++) {
      float4 wv2 = wr4[e * (H_DIM / 4) + c];
      acc[e] += xv.x * wv2.x + xv.y * wv2.y + xv.z * wv2.z + xv.w * wv2.w;
    }
  }
#pragma unroll
  for (int e = 0; e < NE; e++) {
#pragma unroll
    for (int off = 32; off > 0; off >>= 1) acc[e] += __shfl_xor(acc[e], off, 64);
  }
  if (lane == 0) {
    float p[NE];
#pragma unroll
    for (int e = 0; e < NE; e++) p[e] = 1.f / (1.f + expf(-(acc[e] + rbias[e])));
    int e0 = 0;
#pragma unroll
    for (int e = 1; e < NE; e++) if (p[e] > p[e0]) e0 = e;
    int e1 = -1;
#pragma unroll
    for (int e = 0; e < NE; e++) if (e != e0 && (e1 < 0 || p[e] > p[e1])) e1 = e;
    float s = p[e0] + p[e1];
    tE[t * 2] = e0; tE[t * 2 + 1] = e1;
    tG[t * 2] = p[e0] / s; tG[t * 2 + 1] = p[e1] / s;
  }
}

// Slot assignment: LDS histogram over tE -> counts, list, tP (R13 win:
// replaces 8192 serialized device-scope L2 RMWs with LDS atomics).
__global__ __launch_bounds__(1024) void k_sched(
    const int* __restrict__ tE, int* __restrict__ counts,
    int* __restrict__ list, int* __restrict__ tP) {
  __shared__ int lc[NE];
  int tid = threadIdx.x;
  if (tid < NE) lc[tid] = 0;
  __syncthreads();
  for (int t = tid; t < NT; t += 1024) {
    int e0 = tE[t * 2], e1 = tE[t * 2 + 1];
    int p0 = atomicAdd(&lc[e0], 1);
    list[e0 * NT + p0] = t;
    tP[t * 2] = p0;
    int p1 = atomicAdd(&lc[e1], 1);
    list[e1 * NT + p1] = t;
    tP[t * 2 + 1] = p1;
  }
  __syncthreads();
  if (tid < NE) counts[tid] = lc[tid];
}

// ---------------------------------------------------------------------------
// Fused gate+up GEMM (verified m97 config: 128 rows x 64 i-cols x {g,u},
// BK=64, 4 waves, 64 KB dbuf LDS -> 2 blocks/CU, bf16 precast weights via
// global_load_lds). Grid z: z<9 GEMM, z>=9 wd/sd cast riding along (down
// consumes wdb/sdb only in the next launch).
// ---------------------------------------------------------------------------
__global__ __launch_bounds__(256, 2) void k_upgate97(
    const __bf16* __restrict__ xb, const __bf16* __restrict__ wgb,
    const __bf16* __restrict__ wub, const __bf16* __restrict__ sgb,
    const __bf16* __restrict__ sub, const int* __restrict__ counts,
    const int* __restrict__ list,
    __bf16* __restrict__ hs, __bf16* __restrict__ hr,
    const float* __restrict__ wd, const float* __restrict__ sdw,
    __bf16* __restrict__ wdb, __bf16* __restrict__ sdb) {
  int z = blockIdx.z;
  if (z >= NE + 1) {
    // ---- wd/sd cast: (z-9) in [0,9) -> 9216 blocks, 1 chunk/thread ----
    int id = (((z - (NE + 1)) * 32 + blockIdx.y) * 32 + blockIdx.x) * 256 + threadIdx.x;
    if (id < (1 << 21)) castchunk_nt(wd, wdb, id);
    else castchunk_nt(sdw, sdb, id - (1 << 21));
    return;
  }
  int m0 = blockIdx.y * 128, n0 = blockIdx.x * 64;
  bool sh = (z == NE);
  int count, base = 0;
  const __bf16 *Bg, *Bu;
  if (sh) {
    count = NT; Bg = sgb; Bu = sub;
  } else {
    count = counts[z];
    if (m0 >= count) return;
    for (int e = 0; e < z; e++) base += counts[e];
    Bg = wgb + (size_t)z * (I_DIM * H_DIM);
    Bu = wub + (size_t)z * (I_DIM * H_DIM);
  }

  __shared__ bf16x8 lds[4096];   // [2][A 1024 | B 1024] = 64 KB

  int tid = threadIdx.x, lane = tid & 63, w = tid >> 6;
  int wr = w >> 1, wc = w & 1;
  int fr = lane & 15, fs = lane >> 4;

  const bf16x8* a8 = (const bf16x8*)xb;
  const bf16x8* g8 = (const bf16x8*)Bg;
  const bf16x8* u8 = (const bf16x8*)Bu;

  const bf16x8* pA[4];
  const bf16x8* pB[4];
#pragma unroll
  for (int q = 0; q < 4; q++) {
    int c = q * 256 + tid;                  // chunk 0..1023 (128 rows x 8)
    int r = c >> 3, j = (c & 7) ^ (r & 7);
    int gr = m0 + r;
    int tok = sh ? gr : ((gr < count) ? list[z * NT + gr] : list[z * NT]);
    pA[q] = a8 + (size_t)tok * (H_DIM / 8) + j;
    int G = r >> 6, gu = (r >> 5) & 1, cc = r & 31;
    pB[q] = (gu ? u8 : g8) + (size_t)(n0 + G * 32 + cc) * (H_DIM / 8) + j;
  }

  f32x4 acc[4][4];
#pragma unroll
  for (int m = 0; m < 4; m++)
#pragma unroll
    for (int n = 0; n < 4; n++) acc[m][n] = (f32x4){0.f, 0.f, 0.f, 0.f};

  // prologue: stage tile 0 into buf 0
  {
    bf16x8* dA = lds;
    bf16x8* dB = lds + 1024;
#pragma unroll
    for (int q = 0; q < 4; q++) {
      gl16(pA[q], dA + q * 256 + w * 64);
      gl16(pB[q], dB + q * 256 + w * 64);
    }
  }

  const int NK = H_DIM / 64;  // 16
  for (int kt = 0; kt < NK; ++kt) {
    __syncthreads();           // drains tile kt's loads; WAR-fences buf^1
    if (kt + 1 < NK) {
      bf16x8* dA = lds + ((kt + 1) & 1) * 2048;
      bf16x8* dB = dA + 1024;
      int ko = (kt + 1) * 8;
#pragma unroll
      for (int q = 0; q < 4; q++) {
        gl16(pA[q] + ko, dA + q * 256 + w * 64);
        gl16(pB[q] + ko, dB + q * 256 + w * 64);
      }
    }
    const bf16x8* Ac = lds + (kt & 1) * 2048;
    const bf16x8* Bc = Ac + 1024;
#pragma unroll
    for (int ks = 0; ks < 2; ks++) {
      bf16x8 af[4], bfr[4];
#pragma unroll
      for (int mf = 0; mf < 4; mf++) af[mf] = Ac[swzc(wr * 64 + mf * 16 + fr, ks * 4 + fs)];
#pragma unroll
      for (int nf = 0; nf < 4; nf++) bfr[nf] = Bc[swzc(wc * 64 + nf * 16 + fr, ks * 4 + fs)];
      __builtin_amdgcn_s_setprio(1);
#pragma unroll
      for (int m = 0; m < 4; m++)
#pragma unroll
        for (int n = 0; n < 4; n++)
          acc[m][n] = __builtin_amdgcn_mfma_f32_16x16x32_bf16(af[m], bfr[n], acc[m][n], 0, 0, 0);
      __builtin_amdgcn_s_setprio(0);
    }
  }

  // epilogue: h = silu(g)*u; g = acc[m][np], u = acc[m][np+2]
#pragma unroll
  for (int m = 0; m < 4; m++)
#pragma unroll
    for (int np = 0; np < 2; np++)
#pragma unroll
      for (int q2 = 0; q2 < 4; q2++) {
        int row = wr * 64 + m * 16 + fs * 4 + q2;
        int col = n0 + wc * 32 + np * 16 + fr;
        float g = acc[m][np][q2], u = acc[m][np + 2][q2];
        float h = g * u / (1.f + expf(-g));
        __bf16 hb = (__bf16)h;
        int grow = m0 + row;
        if (sh) hs[(size_t)grow * I_DIM + col] = hb;
        else if (grow < count) hr[(size_t)(base + grow) * I_DIM + col] = hb;
      }
}

// ---------------------------------------------------------------------------
// Down GEMM (verified): 128x128 tile, BK=64, 4 waves, 64 KB dbuf LDS ->
// 2 blocks/CU. Routed output y now bf16 (0.4% rel error, halves y traffic).
// ---------------------------------------------------------------------------
__global__ __launch_bounds__(256, 2) void k_down97(
    const __bf16* __restrict__ hs, const __bf16* __restrict__ hr,
    const __bf16* __restrict__ wdb, const __bf16* __restrict__ sdb,
    const int* __restrict__ counts,
    float* __restrict__ out, __bf16* __restrict__ y) {
  int z = blockIdx.z;
  int m0 = blockIdx.y * 128, n0 = blockIdx.x * 128;
  bool sh = (z == NE);
  int count, base = 0;
  const __bf16 *B, *A;
  if (sh) {
    count = NT; B = sdb; A = hs;
  } else {
    count = counts[z];
    if (m0 >= count) return;
    for (int e = 0; e < z; e++) base += counts[e];
    B = wdb + (size_t)z * (H_DIM * I_DIM);
    A = hr + (size_t)base * I_DIM;
  }

  __shared__ bf16x8 lds[4096];   // [2][A 1024 | B 1024] = 64 KB

  int tid = threadIdx.x, lane = tid & 63, w = tid >> 6;
  int wr = w >> 1, wc = w & 1;
  int fr = lane & 15, fs = lane >> 4;

  const bf16x8* a8 = (const bf16x8*)A;
  const bf16x8* b8 = (const bf16x8*)B;

  const bf16x8* pA[4];
  const bf16x8* pB[4];
#pragma unroll
  for (int q = 0; q < 4; q++) {
    int c = q * 256 + tid;                  // chunk 0..1023 (128 rows x 8)
    int r = c >> 3, j = (c & 7) ^ (r & 7);
    int ra = m0 + r; if (ra >= count) ra = count - 1;
    pA[q] = a8 + (size_t)ra * (I_DIM / 8) + j;
    pB[q] = b8 + (size_t)(n0 + r) * (I_DIM / 8) + j;
  }

  f32x4 acc[4][4];
#pragma unroll
  for (int m = 0; m < 4; m++)
#pragma unroll
    for (int n = 0; n < 4; n++) acc[m][n] = (f32x4){0.f, 0.f, 0.f, 0.f};

  // prologue: stage tile 0 into buf 0
  {
    bf16x8* dA = lds;
    bf16x8* dB = lds + 1024;
#pragma unroll
    for (int q = 0; q < 4; q++) {
      gl16(pA[q], dA + q * 256 + w * 64);
      gl16(pB[q], dB + q * 256 + w * 64);
    }
  }

  const int NK = I_DIM / 64;  // 32
  for (int kt = 0; kt < NK; ++kt) {
    __syncthreads();           // drains tile kt's loads; WAR-fences buf^1
    if (kt + 1 < NK) {
      bf16x8* dA = lds + ((kt + 1) & 1) * 2048;
      bf16x8* dB = dA + 1024;
      int ko = (kt + 1) * 8;
#pragma unroll
      for (int q = 0; q < 4; q++) {
        gl16(pA[q] + ko, dA + q * 256 + w * 64);
        gl16(pB[q] + ko, dB + q * 256 + w * 64);
      }
    }
    const bf16x8* Ac = lds + (kt & 1) * 2048;
    const bf16x8* Bc = Ac + 1024;
#pragma unroll
    for (int ks = 0; ks < 2; ks++) {
      bf16x8 af[4], bfr[4];
#pragma unroll
      for (int mf = 0; mf < 4; mf++) af[mf] = Ac[swzc(wr * 64 + mf * 16 + fr, ks * 4 + fs)];
#pragma unroll
      for (int nf = 0; nf < 4; nf++) bfr[nf] = Bc[swzc(wc * 64 + nf * 16 + fr, ks * 4 + fs)];
      __builtin_amdgcn_s_setprio(1);
#pragma unroll
      for (int m = 0; m < 4; m++)
#pragma unroll
        for (int n = 0; n < 4; n++)
          acc[m][n] = __builtin_amdgcn_mfma_f32_16x16x32_bf16(af[m], bfr[n], acc[m][n], 0, 0, 0);
      __builtin_amdgcn_s_setprio(0);
    }
  }

#pragma unroll
  for (int m = 0; m < 4; m++)
#pragma unroll
    for (int n = 0; n < 4; n++)
#pragma unroll
      for (int q2 = 0; q2 < 4; q2++) {
        int row = wr * 64 + m * 16 + fs * 4 + q2;
        int col = n0 + wc * 64 + n * 16 + fr;
        float v = acc[m][n][q2];
        int grow = m0 + row;
        if (sh) out[(size_t)grow * H_DIM + col] = v;
        else if (grow < count) y[(size_t)(base + grow) * H_DIM + col] = (__bf16)v;
      }
}

__global__ __launch_bounds__(256) void k_combine(
    const __bf16* __restrict__ y, const int* __restrict__ counts,
    const int* __restrict__ tE, const int* __restrict__ tP,
    const float* __restrict__ tG, float* __restrict__ out) {
  int t = blockIdx.x;
  int c = threadIdx.x;  // H/4 = 256 quads per token row
  int bases[NE];
  int s = 0;
#pragma unroll
  for (int e = 0; e < NE; e++) { bases[e] = s; s += counts[e]; }
  int e0 = tE[t * 2], e1 = tE[t * 2 + 1];
  int r0 = bases[e0] + tP[t * 2], r1 = bases[e1] + tP[t * 2 + 1];
  float g0 = tG[t * 2], g1 = tG[t * 2 + 1];
  const bf16x4* y4 = (const bf16x4*)y;
  float4* o4 = (float4*)out;
  float4 sv = o4[(size_t)t * (H_DIM / 4) + c];
  bf16x4 a = y4[(size_t)r0 * (H_DIM / 4) + c];
  bf16x4 b = y4[(size_t)r1 * (H_DIM / 4) + c];
  sv.x += g0 * (float)a[0] + g1 * (float)b[0];
  sv.y += g0 * (float)a[1] + g1 * (float)b[1];
  sv.z += g0 * (float)a[2] + g1 * (float)b[2];
  sv.w += g0 * (float)a[3] + g1 * (float)b[3];
  o4[(size_t)t * (H_DIM / 4) + c] = sv;
}

extern "C" void kernel_launch(void* const* d_in, const int* in_sizes, int n_in,
                              void* d_out, int out_size, void* d_ws, size_t ws_size,
                              hipStream_t stream) {
  const float* x = (const float*)d_in[0];
  const float* sg_w = (const float*)d_in[1];
  const float* su_w = (const float*)d_in[2];
  const float* sd_w = (const float*)d_in[3];
  const float* router_w = (const float*)d_in[4];
  const float* routing_bias = (const float*)d_in[5];
  const float* wg = (const float*)d_in[6];
  const float* wu = (const float*)d_in[7];
  const float* wd = (const float*)d_in[8];
  float* out = (float*)d_out;
  char* ws = (char*)d_ws;

  __bf16* xb  = (__bf16*)(ws + 0);            //  8,388,608
  __bf16* hs  = (__bf16*)(ws + 8388608);      // 16,777,216
  __bf16* hr  = (__bf16*)(ws + 25165824);     // 33,554,432
  __bf16* y   = (__bf16*)(ws + 58720256);     // 16,777,216 (bf16 now)
  __bf16* wgb = (__bf16*)(ws + 92274688);     // 33,554,432
  __bf16* wub = (__bf16*)(ws + 125829120);    // 33,554,432
  __bf16* wdb = (__bf16*)(ws + 159383552);    // 33,554,432
  __bf16* sgb = (__bf16*)(ws + 192937984);    //  4,194,304
  __bf16* sub = (__bf16*)(ws + 197132288);    //  4,194,304
  __bf16* sdb = (__bf16*)(ws + 201326592);    //  4,194,304
  int* counts = (int*)(ws + 205520896);
  int* list   = (int*)(ws + 205520960);       // 131,072
  int* tE     = (int*)(ws + 205652032);       // 32,768
  int* tP     = (int*)(ws + 205684800);       // 32,768
  float* tG   = (float*)(ws + 205717568);     // 32,768

  // prep: wg/wu/sg/su cast (nontemporal) + router scoring (no atomics)
  k_prep<<<NBW + NBS + NT / 4, 256, 0, stream>>>(
      wg, wu, sg_w, su_w, wgb, wub, sgb, sub,
      x, router_w, routing_bias, xb, tE, tG);
  // slot assignment via LDS histogram (writes counts/list/tP)
  k_sched<<<1, 1024, 0, stream>>>(tE, counts, list, tP);
  // upgate GEMM (z<9) + wd/sd cast riding along (z in [9,18))
  dim3 gu(I_DIM / 64, NT / 128, (NE + 1) + 9);
  k_upgate97<<<gu, 256, 0, stream>>>(xb, wgb, wub, sgb, sub, counts, list,
                                     hs, hr, wd, sd_w, wdb, sdb);
  dim3 gd(H_DIM / 128, NT / 128, NE + 1);
  k_down97<<<gd, 256, 0, stream>>>(hs, hr, wdb, sdb, counts, out, y);
  k_combine<<<NT, 256, 0, stream>>>(y, counts, tE, tP, tG, out);
}

// Round 15
// 277.293 us; speedup vs baseline: 1.0769x; 1.0769x over previous
//
#include <hip/hip_runtime.h>
#include <hip/hip_bf16.h>

#define H_DIM 1024
#define I_DIM 2048
#define NE 8
#define NT 4096

typedef __bf16 bf16x8 __attribute__((ext_vector_type(8)));
typedef __bf16 bf16x4 __attribute__((ext_vector_type(4)));
typedef float f32x4 __attribute__((ext_vector_type(4)));

// 16B-chunk index within a [rows][8-chunk] LDS tile, XOR-swizzled (verified
// conflict-free R1-R14: SQ_LDS_BANK_CONFLICT == 0).
__device__ __forceinline__ int swzc(int r, int j) { return r * 8 + (j ^ (r & 7)); }

// async global->LDS, 16B per lane. LDS dest is wave-uniform base (HW adds lane*16).
__device__ __forceinline__ void gl16(const void* g, void* l) {
  __builtin_amdgcn_global_load_lds(
      (const __attribute__((address_space(1))) unsigned int*)g,
      (__attribute__((address_space(3))) unsigned int*)l, 16, 0, 0);
}

__device__ __forceinline__ bf16x8 cvt8(float4 a, float4 b) {
  bf16x8 r;
  r[0] = (__bf16)a.x; r[1] = (__bf16)a.y; r[2] = (__bf16)a.z; r[3] = (__bf16)a.w;
  r[4] = (__bf16)b.x; r[5] = (__bf16)b.y; r[6] = (__bf16)b.z; r[7] = (__bf16)b.w;
  return r;
}

// plain cached fp32->bf16 chunk cast (R14's nontemporal variant REGRESSED:
// nt stores are slower and forfeit L3 residency that k_down97 exploits)
__device__ __forceinline__ void castchunk(const float* s, __bf16* d, int off) {
  const float4* s4 = (const float4*)s;
  float4 a = s4[(size_t)off * 2], b = s4[(size_t)off * 2 + 1];
  ((bf16x8*)d)[off] = cvt8(a, b);
}

#define NBW 16384   // wg+wu cast blocks: 2 * 2^21 chunks / 256
#define NBS 2048    // sg+su cast blocks: 2 * 2^18 chunks / 256

// Prep: cast upgate's weights (wg,wu,sg,su) + router SCORING ONLY (no
// atomics — slot assignment in k_sched's LDS histogram, R13 win).
__global__ __launch_bounds__(256) void k_prep(
    const float* __restrict__ wg, const float* __restrict__ wu,
    const float* __restrict__ sg, const float* __restrict__ su,
    __bf16* __restrict__ wgb, __bf16* __restrict__ wub,
    __bf16* __restrict__ sgb, __bf16* __restrict__ sub,
    const float* __restrict__ x, const float* __restrict__ rw,
    const float* __restrict__ rbias, __bf16* __restrict__ xb,
    int* __restrict__ tE, float* __restrict__ tG) {
  if (blockIdx.x < NBW + NBS) {
    const float* s; __bf16* d; int off;
    if (blockIdx.x < NBW) {
      int i = blockIdx.x * 256 + threadIdx.x;
      if (i < (1 << 21)) { s = wg; d = wgb; off = i; }
      else { s = wu; d = wub; off = i - (1 << 21); }
    } else {
      int i = (blockIdx.x - NBW) * 256 + threadIdx.x;
      if (i < (1 << 18)) { s = sg; d = sgb; off = i; }
      else { s = su; d = sub; off = i - (1 << 18); }
    }
    castchunk(s, d, off);
    return;
  }
  // ---- router scoring (sigmoid top-2 renorm; fuses x->bf16; NO atomics) ----
  int blk = blockIdx.x - (NBW + NBS);         // 0..1023
  int wv = threadIdx.x >> 6, lane = threadIdx.x & 63;
  int t = blk * 4 + wv;
  float acc[NE];
#pragma unroll
  for (int e = 0; e < NE; e++) acc[e] = 0.f;
  const float4* xr = (const float4*)(x + (size_t)t * H_DIM);
  const float4* wr4 = (const float4*)rw;
  bf16x4* xo = (bf16x4*)xb + (size_t)t * (H_DIM / 4);
#pragma unroll
  for (int it = 0; it < 4; ++it) {
    int c = it * 64 + lane;
    float4 xv = xr[c];
    bf16x4 bv;
    bv[0] = (__bf16)xv.x; bv[1] = (__bf16)xv.y;
    bv[2] = (__bf16)xv.z; bv[3] = (__bf16)xv.w;
    xo[c] = bv;
#pragma unroll
    for (int e = 0; e < NE; e++) {
      float4 wv2 = wr4[e * (H_DIM / 4) + c];
      acc[e] += xv.x * wv2.x + xv.y * wv2.y + xv.z * wv2.z + xv.w * wv2.w;
    }
  }
#pragma unroll
  for (int e = 0; e < NE; e++) {
#pragma unroll
    for (int off = 32; off > 0; off >>= 1) acc[e] += __shfl_xor(acc[e], off, 64);
  }
  if (lane == 0) {
    float p[NE];
#pragma unroll
    for (int e = 0; e < NE; e++) p[e] = 1.f / (1.f + expf(-(acc[e] + rbias[e])));
    int e0 = 0;
#pragma unroll
    for (int e = 1; e < NE; e++) if (p[e] > p[e0]) e0 = e;
    int e1 = -1;
#pragma unroll
    for (int e = 0; e < NE; e++) if (e != e0 && (e1 < 0 || p[e] > p[e1])) e1 = e;
    float s = p[e0] + p[e1];
    tE[t * 2] = e0; tE[t * 2 + 1] = e1;
    tG[t * 2] = p[e0] / s; tG[t * 2 + 1] = p[e1] / s;
  }
}

// Slot assignment: LDS histogram over tE -> counts, list, tP (R13 win:
// replaces 8192 serialized device-scope L2 RMWs with LDS atomics).
__global__ __launch_bounds__(1024) void k_sched(
    const int* __restrict__ tE, int* __restrict__ counts,
    int* __restrict__ list, int* __restrict__ tP) {
  __shared__ int lc[NE];
  int tid = threadIdx.x;
  if (tid < NE) lc[tid] = 0;
  __syncthreads();
  for (int t = tid; t < NT; t += 1024) {
    int e0 = tE[t * 2], e1 = tE[t * 2 + 1];
    int p0 = atomicAdd(&lc[e0], 1);
    list[e0 * NT + p0] = t;
    tP[t * 2] = p0;
    int p1 = atomicAdd(&lc[e1], 1);
    list[e1 * NT + p1] = t;
    tP[t * 2 + 1] = p1;
  }
  __syncthreads();
  if (tid < NE) counts[tid] = lc[tid];
}

// ---------------------------------------------------------------------------
// Fused gate+up GEMM (verified m97 config: 128 rows x 64 i-cols x {g,u},
// BK=64, 4 waves, 64 KB dbuf LDS -> 2 blocks/CU, bf16 precast weights via
// global_load_lds). Grid z: z<9 GEMM, z>=9 wd/sd cast riding along (down
// consumes wdb/sdb only in the next launch).
// ---------------------------------------------------------------------------
__global__ __launch_bounds__(256, 2) void k_upgate97(
    const __bf16* __restrict__ xb, const __bf16* __restrict__ wgb,
    const __bf16* __restrict__ wub, const __bf16* __restrict__ sgb,
    const __bf16* __restrict__ sub, const int* __restrict__ counts,
    const int* __restrict__ list,
    __bf16* __restrict__ hs, __bf16* __restrict__ hr,
    const float* __restrict__ wd, const float* __restrict__ sdw,
    __bf16* __restrict__ wdb, __bf16* __restrict__ sdb) {
  int z = blockIdx.z;
  if (z >= NE + 1) {
    // ---- wd/sd cast: (z-9) in [0,9) -> 9216 blocks, 1 chunk/thread ----
    int id = (((z - (NE + 1)) * 32 + blockIdx.y) * 32 + blockIdx.x) * 256 + threadIdx.x;
    if (id < (1 << 21)) castchunk(wd, wdb, id);
    else castchunk(sdw, sdb, id - (1 << 21));
    return;
  }
  int m0 = blockIdx.y * 128, n0 = blockIdx.x * 64;
  bool sh = (z == NE);
  int count, base = 0;
  const __bf16 *Bg, *Bu;
  if (sh) {
    count = NT; Bg = sgb; Bu = sub;
  } else {
    count = counts[z];
    if (m0 >= count) return;
    for (int e = 0; e < z; e++) base += counts[e];
    Bg = wgb + (size_t)z * (I_DIM * H_DIM);
    Bu = wub + (size_t)z * (I_DIM * H_DIM);
  }

  __shared__ bf16x8 lds[4096];   // [2][A 1024 | B 1024] = 64 KB

  int tid = threadIdx.x, lane = tid & 63, w = tid >> 6;
  int wr = w >> 1, wc = w & 1;
  int fr = lane & 15, fs = lane >> 4;

  const bf16x8* a8 = (const bf16x8*)xb;
  const bf16x8* g8 = (const bf16x8*)Bg;
  const bf16x8* u8 = (const bf16x8*)Bu;

  const bf16x8* pA[4];
  const bf16x8* pB[4];
#pragma unroll
  for (int q = 0; q < 4; q++) {
    int c = q * 256 + tid;                  // chunk 0..1023 (128 rows x 8)
    int r = c >> 3, j = (c & 7) ^ (r & 7);
    int gr = m0 + r;
    int tok = sh ? gr : ((gr < count) ? list[z * NT + gr] : list[z * NT]);
    pA[q] = a8 + (size_t)tok * (H_DIM / 8) + j;
    int G = r >> 6, gu = (r >> 5) & 1, cc = r & 31;
    pB[q] = (gu ? u8 : g8) + (size_t)(n0 + G * 32 + cc) * (H_DIM / 8) + j;
  }

  f32x4 acc[4][4];
#pragma unroll
  for (int m = 0; m < 4; m++)
#pragma unroll
    for (int n = 0; n < 4; n++) acc[m][n] = (f32x4){0.f, 0.f, 0.f, 0.f};

  // prologue: stage tile 0 into buf 0
  {
    bf16x8* dA = lds;
    bf16x8* dB = lds + 1024;
#pragma unroll
    for (int q = 0; q < 4; q++) {
      gl16(pA[q], dA + q * 256 + w * 64);
      gl16(pB[q], dB + q * 256 + w * 64);
    }
  }

  const int NK = H_DIM / 64;  // 16
  for (int kt = 0; kt < NK; ++kt) {
    __syncthreads();           // drains tile kt's loads; WAR-fences buf^1
    if (kt + 1 < NK) {
      bf16x8* dA = lds + ((kt + 1) & 1) * 2048;
      bf16x8* dB = dA + 1024;
      int ko = (kt + 1) * 8;
#pragma unroll
      for (int q = 0; q < 4; q++) {
        gl16(pA[q] + ko, dA + q * 256 + w * 64);
        gl16(pB[q] + ko, dB + q * 256 + w * 64);
      }
    }
    const bf16x8* Ac = lds + (kt & 1) * 2048;
    const bf16x8* Bc = Ac + 1024;
#pragma unroll
    for (int ks = 0; ks < 2; ks++) {
      bf16x8 af[4], bfr[4];
#pragma unroll
      for (int mf = 0; mf < 4; mf++) af[mf] = Ac[swzc(wr * 64 + mf * 16 + fr, ks * 4 + fs)];
#pragma unroll
      for (int nf = 0; nf < 4; nf++) bfr[nf] = Bc[swzc(wc * 64 + nf * 16 + fr, ks * 4 + fs)];
      __builtin_amdgcn_s_setprio(1);
#pragma unroll
      for (int m = 0; m < 4; m++)
#pragma unroll
        for (int n = 0; n < 4; n++)
          acc[m][n] = __builtin_amdgcn_mfma_f32_16x16x32_bf16(af[m], bfr[n], acc[m][n], 0, 0, 0);
      __builtin_amdgcn_s_setprio(0);
    }
  }

  // epilogue: h = silu(g)*u; g = acc[m][np], u = acc[m][np+2]
#pragma unroll
  for (int m = 0; m < 4; m++)
#pragma unroll
    for (int np = 0; np < 2; np++)
#pragma unroll
      for (int q2 = 0; q2 < 4; q2++) {
        int row = wr * 64 + m * 16 + fs * 4 + q2;
        int col = n0 + wc * 32 + np * 16 + fr;
        float g = acc[m][np][q2], u = acc[m][np + 2][q2];
        float h = g * u / (1.f + expf(-g));
        __bf16 hb = (__bf16)h;
        int grow = m0 + row;
        if (sh) hs[(size_t)grow * I_DIM + col] = hb;
        else if (grow < count) hr[(size_t)(base + grow) * I_DIM + col] = hb;
      }
}

// ---------------------------------------------------------------------------
// Down GEMM (verified): 128x128 tile, BK=64, 4 waves, 64 KB dbuf LDS ->
// 2 blocks/CU. Routed output y bf16 (0.4% rel error, halves y traffic).
// ---------------------------------------------------------------------------
__global__ __launch_bounds__(256, 2) void k_down97(
    const __bf16* __restrict__ hs, const __bf16* __restrict__ hr,
    const __bf16* __restrict__ wdb, const __bf16* __restrict__ sdb,
    const int* __restrict__ counts,
    float* __restrict__ out, __bf16* __restrict__ y) {
  int z = blockIdx.z;
  int m0 = blockIdx.y * 128, n0 = blockIdx.x * 128;
  bool sh = (z == NE);
  int count, base = 0;
  const __bf16 *B, *A;
  if (sh) {
    count = NT; B = sdb; A = hs;
  } else {
    count = counts[z];
    if (m0 >= count) return;
    for (int e = 0; e < z; e++) base += counts[e];
    B = wdb + (size_t)z * (H_DIM * I_DIM);
    A = hr + (size_t)base * I_DIM;
  }

  __shared__ bf16x8 lds[4096];   // [2][A 1024 | B 1024] = 64 KB

  int tid = threadIdx.x, lane = tid & 63, w = tid >> 6;
  int wr = w >> 1, wc = w & 1;
  int fr = lane & 15, fs = lane >> 4;

  const bf16x8* a8 = (const bf16x8*)A;
  const bf16x8* b8 = (const bf16x8*)B;

  const bf16x8* pA[4];
  const bf16x8* pB[4];
#pragma unroll
  for (int q = 0; q < 4; q++) {
    int c = q * 256 + tid;                  // chunk 0..1023 (128 rows x 8)
    int r = c >> 3, j = (c & 7) ^ (r & 7);
    int ra = m0 + r; if (ra >= count) ra = count - 1;
    pA[q] = a8 + (size_t)ra * (I_DIM / 8) + j;
    pB[q] = b8 + (size_t)(n0 + r) * (I_DIM / 8) + j;
  }

  f32x4 acc[4][4];
#pragma unroll
  for (int m = 0; m < 4; m++)
#pragma unroll
    for (int n = 0; n < 4; n++) acc[m][n] = (f32x4){0.f, 0.f, 0.f, 0.f};

  // prologue: stage tile 0 into buf 0
  {
    bf16x8* dA = lds;
    bf16x8* dB = lds + 1024;
#pragma unroll
    for (int q = 0; q < 4; q++) {
      gl16(pA[q], dA + q * 256 + w * 64);
      gl16(pB[q], dB + q * 256 + w * 64);
    }
  }

  const int NK = I_DIM / 64;  // 32
  for (int kt = 0; kt < NK; ++kt) {
    __syncthreads();           // drains tile kt's loads; WAR-fences buf^1
    if (kt + 1 < NK) {
      bf16x8* dA = lds + ((kt + 1) & 1) * 2048;
      bf16x8* dB = dA + 1024;
      int ko = (kt + 1) * 8;
#pragma unroll
      for (int q = 0; q < 4; q++) {
        gl16(pA[q] + ko, dA + q * 256 + w * 64);
        gl16(pB[q] + ko, dB + q * 256 + w * 64);
      }
    }
    const bf16x8* Ac = lds + (kt & 1) * 2048;
    const bf16x8* Bc = Ac + 1024;
#pragma unroll
    for (int ks = 0; ks < 2; ks++) {
      bf16x8 af[4], bfr[4];
#pragma unroll
      for (int mf = 0; mf < 4; mf++) af[mf] = Ac[swzc(wr * 64 + mf * 16 + fr, ks * 4 + fs)];
#pragma unroll
      for (int nf = 0; nf < 4; nf++) bfr[nf] = Bc[swzc(wc * 64 + nf * 16 + fr, ks * 4 + fs)];
      __builtin_amdgcn_s_setprio(1);
#pragma unroll
      for (int m = 0; m < 4; m++)
#pragma unroll
        for (int n = 0; n < 4; n++)
          acc[m][n] = __builtin_amdgcn_mfma_f32_16x16x32_bf16(af[m], bfr[n], acc[m][n], 0, 0, 0);
      __builtin_amdgcn_s_setprio(0);
    }
  }

#pragma unroll
  for (int m = 0; m < 4; m++)
#pragma unroll
    for (int n = 0; n < 4; n++)
#pragma unroll
      for (int q2 = 0; q2 < 4; q2++) {
        int row = wr * 64 + m * 16 + fs * 4 + q2;
        int col = n0 + wc * 64 + n * 16 + fr;
        float v = acc[m][n][q2];
        int grow = m0 + row;
        if (sh) out[(size_t)grow * H_DIM + col] = v;
        else if (grow < count) y[(size_t)(base + grow) * H_DIM + col] = (__bf16)v;
      }
}

__global__ __launch_bounds__(256) void k_combine(
    const __bf16* __restrict__ y, const int* __restrict__ counts,
    const int* __restrict__ tE, const int* __restrict__ tP,
    const float* __restrict__ tG, float* __restrict__ out) {
  int t = blockIdx.x;
  int c = threadIdx.x;  // H/4 = 256 quads per token row
  int bases[NE];
  int s = 0;
#pragma unroll
  for (int e = 0; e < NE; e++) { bases[e] = s; s += counts[e]; }
  int e0 = tE[t * 2], e1 = tE[t * 2 + 1];
  int r0 = bases[e0] + tP[t * 2], r1 = bases[e1] + tP[t * 2 + 1];
  float g0 = tG[t * 2], g1 = tG[t * 2 + 1];
  const bf16x4* y4 = (const bf16x4*)y;
  float4* o4 = (float4*)out;
  float4 sv = o4[(size_t)t * (H_DIM / 4) + c];
  bf16x4 a = y4[(size_t)r0 * (H_DIM / 4) + c];
  bf16x4 b = y4[(size_t)r1 * (H_DIM / 4) + c];
  sv.x += g0 * (float)a[0] + g1 * (float)b[0];
  sv.y += g0 * (float)a[1] + g1 * (float)b[1];
  sv.z += g0 * (float)a[2] + g1 * (float)b[2];
  sv.w += g0 * (float)a[3] + g1 * (float)b[3];
  o4[(size_t)t * (H_DIM / 4) + c] = sv;
}

extern "C" void kernel_launch(void* const* d_in, const int* in_sizes, int n_in,
                              void* d_out, int out_size, void* d_ws, size_t ws_size,
                              hipStream_t stream) {
  const float* x = (const float*)d_in[0];
  const float* sg_w = (const float*)d_in[1];
  const float* su_w = (const float*)d_in[2];
  const float* sd_w = (const float*)d_in[3];
  const float* router_w = (const float*)d_in[4];
  const float* routing_bias = (const float*)d_in[5];
  const float* wg = (const float*)d_in[6];
  const float* wu = (const float*)d_in[7];
  const float* wd = (const float*)d_in[8];
  float* out = (float*)d_out;
  char* ws = (char*)d_ws;

  __bf16* xb  = (__bf16*)(ws + 0);            //  8,388,608
  __bf16* hs  = (__bf16*)(ws + 8388608);      // 16,777,216
  __bf16* hr  = (__bf16*)(ws + 25165824);     // 33,554,432
  __bf16* y   = (__bf16*)(ws + 58720256);     // 16,777,216 (bf16)
  __bf16* wgb = (__bf16*)(ws + 92274688);     // 33,554,432
  __bf16* wub = (__bf16*)(ws + 125829120);    // 33,554,432
  __bf16* wdb = (__bf16*)(ws + 159383552);    // 33,554,432
  __bf16* sgb = (__bf16*)(ws + 192937984);    //  4,194,304
  __bf16* sub = (__bf16*)(ws + 197132288);    //  4,194,304
  __bf16* sdb = (__bf16*)(ws + 201326592);    //  4,194,304
  int* counts = (int*)(ws + 205520896);
  int* list   = (int*)(ws + 205520960);       // 131,072
  int* tE     = (int*)(ws + 205652032);       // 32,768
  int* tP     = (int*)(ws + 205684800);       // 32,768
  float* tG   = (float*)(ws + 205717568);     // 32,768

  // prep: wg/wu/sg/su cast (cached) + router scoring (no atomics)
  k_prep<<<NBW + NBS + NT / 4, 256, 0, stream>>>(
      wg, wu, sg_w, su_w, wgb, wub, sgb, sub,
      x, router_w, routing_bias, xb, tE, tG);
  // slot assignment via LDS histogram (writes counts/list/tP)
  k_sched<<<1, 1024, 0, stream>>>(tE, counts, list, tP);
  // upgate GEMM (z<9) + wd/sd cast riding along (z in [9,18))
  dim3 gu(I_DIM / 64, NT / 128, (NE + 1) + 9);
  k_upgate97<<<gu, 256, 0, stream>>>(xb, wgb, wub, sgb, sub, counts, list,
                                     hs, hr, wd, sd_w, wdb, sdb);
  dim3 gd(H_DIM / 128, NT / 128, NE + 1);
  k_down97<<<gd, 256, 0, stream>>>(hs, hr, wdb, sdb, counts, out, y);
  k_combine<<<NT, 256, 0, stream>>>(y, counts, tE, tP, tG, out);
}

// Round 16
// 265.406 us; speedup vs baseline: 1.1251x; 1.0448x over previous
//
#include <hip/hip_runtime.h>
#include <hip/hip_bf16.h>

#define H_DIM 1024
#define I_DIM 2048
#define NE 8
#define NT 4096

typedef __bf16 bf16x8 __attribute__((ext_vector_type(8)));
typedef __bf16 bf16x4 __attribute__((ext_vector_type(4)));
typedef float f32x4 __attribute__((ext_vector_type(4)));

// 16B-chunk index within a [rows][8-chunk] LDS tile, XOR-swizzled (verified
// conflict-free R1-R15: SQ_LDS_BANK_CONFLICT == 0).
__device__ __forceinline__ int swzc(int r, int j) { return r * 8 + (j ^ (r & 7)); }

// async global->LDS, 16B per lane. LDS dest is wave-uniform base (HW adds lane*16).
__device__ __forceinline__ void gl16(const void* g, void* l) {
  __builtin_amdgcn_global_load_lds(
      (const __attribute__((address_space(1))) unsigned int*)g,
      (__attribute__((address_space(3))) unsigned int*)l, 16, 0, 0);
}

__device__ __forceinline__ bf16x8 cvt8(float4 a, float4 b) {
  bf16x8 r;
  r[0] = (__bf16)a.x; r[1] = (__bf16)a.y; r[2] = (__bf16)a.z; r[3] = (__bf16)a.w;
  r[4] = (__bf16)b.x; r[5] = (__bf16)b.y; r[6] = (__bf16)b.z; r[7] = (__bf16)b.w;
  return r;
}

// plain cached fp32->bf16 chunk cast (nt variant regressed in R14)
__device__ __forceinline__ void castchunk(const float* s, __bf16* d, int off) {
  const float4* s4 = (const float4*)s;
  float4 a = s4[(size_t)off * 2], b = s4[(size_t)off * 2 + 1];
  ((bf16x8*)d)[off] = cvt8(a, b);
}

#define NBW 16384   // wg+wu cast blocks: 2 * 2^21 chunks / 256
#define NBS 2048    // sg+su cast blocks: 2 * 2^18 chunks / 256

// Prep: cast upgate's weights (wg,wu,sg,su) + router SCORING ONLY (no
// atomics — slot assignment in k_sched's LDS histogram, R13 win).
__global__ __launch_bounds__(256) void k_prep(
    const float* __restrict__ wg, const float* __restrict__ wu,
    const float* __restrict__ sg, const float* __restrict__ su,
    __bf16* __restrict__ wgb, __bf16* __restrict__ wub,
    __bf16* __restrict__ sgb, __bf16* __restrict__ sub,
    const float* __restrict__ x, const float* __restrict__ rw,
    const float* __restrict__ rbias, __bf16* __restrict__ xb,
    int* __restrict__ tE, float* __restrict__ tG) {
  if (blockIdx.x < NBW + NBS) {
    const float* s; __bf16* d; int off;
    if (blockIdx.x < NBW) {
      int i = blockIdx.x * 256 + threadIdx.x;
      if (i < (1 << 21)) { s = wg; d = wgb; off = i; }
      else { s = wu; d = wub; off = i - (1 << 21); }
    } else {
      int i = (blockIdx.x - NBW) * 256 + threadIdx.x;
      if (i < (1 << 18)) { s = sg; d = sgb; off = i; }
      else { s = su; d = sub; off = i - (1 << 18); }
    }
    castchunk(s, d, off);
    return;
  }
  // ---- router scoring (sigmoid top-2 renorm; fuses x->bf16; NO atomics) ----
  int blk = blockIdx.x - (NBW + NBS);         // 0..1023
  int wv = threadIdx.x >> 6, lane = threadIdx.x & 63;
  int t = blk * 4 + wv;
  float acc[NE];
#pragma unroll
  for (int e = 0; e < NE; e++) acc[e] = 0.f;
  const float4* xr = (const float4*)(x + (size_t)t * H_DIM);
  const float4* wr4 = (const float4*)rw;
  bf16x4* xo = (bf16x4*)xb + (size_t)t * (H_DIM / 4);
#pragma unroll
  for (int it = 0; it < 4; ++it) {
    int c = it * 64 + lane;
    float4 xv = xr[c];
    bf16x4 bv;
    bv[0] = (__bf16)xv.x; bv[1] = (__bf16)xv.y;
    bv[2] = (__bf16)xv.z; bv[3] = (__bf16)xv.w;
    xo[c] = bv;
#pragma unroll
    for (int e = 0; e < NE; e++) {
      float4 wv2 = wr4[e * (H_DIM / 4) + c];
      acc[e] += xv.x * wv2.x + xv.y * wv2.y + xv.z * wv2.z + xv.w * wv2.w;
    }
  }
#pragma unroll
  for (int e = 0; e < NE; e++) {
#pragma unroll
    for (int off = 32; off > 0; off >>= 1) acc[e] += __shfl_xor(acc[e], off, 64);
  }
  if (lane == 0) {
    float p[NE];
#pragma unroll
    for (int e = 0; e < NE; e++) p[e] = 1.f / (1.f + expf(-(acc[e] + rbias[e])));
    int e0 = 0;
#pragma unroll
    for (int e = 1; e < NE; e++) if (p[e] > p[e0]) e0 = e;
    int e1 = -1;
#pragma unroll
    for (int e = 0; e < NE; e++) if (e != e0 && (e1 < 0 || p[e] > p[e1])) e1 = e;
    float s = p[e0] + p[e1];
    tE[t * 2] = e0; tE[t * 2 + 1] = e1;
    tG[t * 2] = p[e0] / s; tG[t * 2 + 1] = p[e1] / s;
  }
}

// Slot assignment: LDS histogram over tE -> counts, list, tP.
__global__ __launch_bounds__(1024) void k_sched(
    const int* __restrict__ tE, int* __restrict__ counts,
    int* __restrict__ list, int* __restrict__ tP) {
  __shared__ int lc[NE];
  int tid = threadIdx.x;
  if (tid < NE) lc[tid] = 0;
  __syncthreads();
  for (int t = tid; t < NT; t += 1024) {
    int e0 = tE[t * 2], e1 = tE[t * 2 + 1];
    int p0 = atomicAdd(&lc[e0], 1);
    list[e0 * NT + p0] = t;
    tP[t * 2] = p0;
    int p1 = atomicAdd(&lc[e1], 1);
    list[e1 * NT + p1] = t;
    tP[t * 2 + 1] = p1;
  }
  __syncthreads();
  if (tid < NE) counts[tid] = lc[tid];
}

// ---------------------------------------------------------------------------
// Fused gate+up GEMM, TRUE m97 form: 128 rows x 64 i-cols x {g,u}, BK=64,
// 4 waves, SINGLE 32 KB LDS buffer -> 4 blocks/CU (m103: single-buf 912 TF >
// dbuf 839-890; cross-block overlap is the latency-hiding mechanism, m114).
// Per K-tile: {drain-barrier; ds_read+MFMA; WAR-barrier; stage kt+1}.
// Grid z: z<9 GEMM, z>=9 wd/sd cast riding along.
// ---------------------------------------------------------------------------
__global__ __launch_bounds__(256, 4) void k_upgate97(
    const __bf16* __restrict__ xb, const __bf16* __restrict__ wgb,
    const __bf16* __restrict__ wub, const __bf16* __restrict__ sgb,
    const __bf16* __restrict__ sub, const int* __restrict__ counts,
    const int* __restrict__ list,
    __bf16* __restrict__ hs, __bf16* __restrict__ hr,
    const float* __restrict__ wd, const float* __restrict__ sdw,
    __bf16* __restrict__ wdb, __bf16* __restrict__ sdb) {
  int z = blockIdx.z;
  if (z >= NE + 1) {
    // ---- wd/sd cast: (z-9) in [0,9) -> 9216 blocks, 1 chunk/thread ----
    int id = (((z - (NE + 1)) * 32 + blockIdx.y) * 32 + blockIdx.x) * 256 + threadIdx.x;
    if (id < (1 << 21)) castchunk(wd, wdb, id);
    else castchunk(sdw, sdb, id - (1 << 21));
    return;
  }
  int m0 = blockIdx.y * 128, n0 = blockIdx.x * 64;
  bool sh = (z == NE);
  int count, base = 0;
  const __bf16 *Bg, *Bu;
  if (sh) {
    count = NT; Bg = sgb; Bu = sub;
  } else {
    count = counts[z];
    if (m0 >= count) return;
    for (int e = 0; e < z; e++) base += counts[e];
    Bg = wgb + (size_t)z * (I_DIM * H_DIM);
    Bu = wub + (size_t)z * (I_DIM * H_DIM);
  }

  __shared__ bf16x8 lds[2048];   // [A 1024 | B 1024] = 32 KB single buffer

  int tid = threadIdx.x, lane = tid & 63, w = tid >> 6;
  int wr = w >> 1, wc = w & 1;
  int fr = lane & 15, fs = lane >> 4;

  const bf16x8* a8 = (const bf16x8*)xb;
  const bf16x8* g8 = (const bf16x8*)Bg;
  const bf16x8* u8 = (const bf16x8*)Bu;

  const bf16x8* pA[4];
  const bf16x8* pB[4];
#pragma unroll
  for (int q = 0; q < 4; q++) {
    int c = q * 256 + tid;                  // chunk 0..1023 (128 rows x 8)
    int r = c >> 3, j = (c & 7) ^ (r & 7);
    int gr = m0 + r;
    int tok = sh ? gr : ((gr < count) ? list[z * NT + gr] : list[z * NT]);
    pA[q] = a8 + (size_t)tok * (H_DIM / 8) + j;
    int G = r >> 6, gu = (r >> 5) & 1, cc = r & 31;
    pB[q] = (gu ? u8 : g8) + (size_t)(n0 + G * 32 + cc) * (H_DIM / 8) + j;
  }

  f32x4 acc[4][4];
#pragma unroll
  for (int m = 0; m < 4; m++)
#pragma unroll
    for (int n = 0; n < 4; n++) acc[m][n] = (f32x4){0.f, 0.f, 0.f, 0.f};

  bf16x8* dA = lds;
  bf16x8* dB = lds + 1024;
  // prologue: stage tile 0
#pragma unroll
  for (int q = 0; q < 4; q++) {
    gl16(pA[q], dA + q * 256 + w * 64);
    gl16(pB[q], dB + q * 256 + w * 64);
  }

  const int NK = H_DIM / 64;  // 16
  for (int kt = 0; kt < NK; ++kt) {
    __syncthreads();           // drain: tile kt's gl16 landed (vmcnt0+barrier)
#pragma unroll
    for (int ks = 0; ks < 2; ks++) {
      bf16x8 af[4], bfr[4];
#pragma unroll
      for (int mf = 0; mf < 4; mf++) af[mf] = lds[swzc(wr * 64 + mf * 16 + fr, ks * 4 + fs)];
#pragma unroll
      for (int nf = 0; nf < 4; nf++) bfr[nf] = dB[swzc(wc * 64 + nf * 16 + fr, ks * 4 + fs)];
      __builtin_amdgcn_s_setprio(1);
#pragma unroll
      for (int m = 0; m < 4; m++)
#pragma unroll
        for (int n = 0; n < 4; n++)
          acc[m][n] = __builtin_amdgcn_mfma_f32_16x16x32_bf16(af[m], bfr[n], acc[m][n], 0, 0, 0);
      __builtin_amdgcn_s_setprio(0);
    }
    __syncthreads();           // WAR: all waves done reading before restage
    if (kt + 1 < NK) {
      int ko = (kt + 1) * 8;
#pragma unroll
      for (int q = 0; q < 4; q++) {
        gl16(pA[q] + ko, dA + q * 256 + w * 64);
        gl16(pB[q] + ko, dB + q * 256 + w * 64);
      }
    }
  }

  // epilogue: h = silu(g)*u; g = acc[m][np], u = acc[m][np+2]
#pragma unroll
  for (int m = 0; m < 4; m++)
#pragma unroll
    for (int np = 0; np < 2; np++)
#pragma unroll
      for (int q2 = 0; q2 < 4; q2++) {
        int row = wr * 64 + m * 16 + fs * 4 + q2;
        int col = n0 + wc * 32 + np * 16 + fr;
        float g = acc[m][np][q2], u = acc[m][np + 2][q2];
        float h = g * u / (1.f + expf(-g));
        __bf16 hb = (__bf16)h;
        int grow = m0 + row;
        if (sh) hs[(size_t)grow * I_DIM + col] = hb;
        else if (grow < count) hr[(size_t)(base + grow) * I_DIM + col] = hb;
      }
}

// ---------------------------------------------------------------------------
// Down GEMM, TRUE m97 form: 128x128 tile, BK=64, 4 waves, single 32 KB LDS
// -> 4 blocks/CU. Routed output y bf16.
// ---------------------------------------------------------------------------
__global__ __launch_bounds__(256, 4) void k_down97(
    const __bf16* __restrict__ hs, const __bf16* __restrict__ hr,
    const __bf16* __restrict__ wdb, const __bf16* __restrict__ sdb,
    const int* __restrict__ counts,
    float* __restrict__ out, __bf16* __restrict__ y) {
  int z = blockIdx.z;
  int m0 = blockIdx.y * 128, n0 = blockIdx.x * 128;
  bool sh = (z == NE);
  int count, base = 0;
  const __bf16 *B, *A;
  if (sh) {
    count = NT; B = sdb; A = hs;
  } else {
    count = counts[z];
    if (m0 >= count) return;
    for (int e = 0; e < z; e++) base += counts[e];
    B = wdb + (size_t)z * (H_DIM * I_DIM);
    A = hr + (size_t)base * I_DIM;
  }

  __shared__ bf16x8 lds[2048];   // [A 1024 | B 1024] = 32 KB single buffer

  int tid = threadIdx.x, lane = tid & 63, w = tid >> 6;
  int wr = w >> 1, wc = w & 1;
  int fr = lane & 15, fs = lane >> 4;

  const bf16x8* a8 = (const bf16x8*)A;
  const bf16x8* b8 = (const bf16x8*)B;

  const bf16x8* pA[4];
  const bf16x8* pB[4];
#pragma unroll
  for (int q = 0; q < 4; q++) {
    int c = q * 256 + tid;                  // chunk 0..1023 (128 rows x 8)
    int r = c >> 3, j = (c & 7) ^ (r & 7);
    int ra = m0 + r; if (ra >= count) ra = count - 1;
    pA[q] = a8 + (size_t)ra * (I_DIM / 8) + j;
    pB[q] = b8 + (size_t)(n0 + r) * (I_DIM / 8) + j;
  }

  f32x4 acc[4][4];
#pragma unroll
  for (int m = 0; m < 4; m++)
#pragma unroll
    for (int n = 0; n < 4; n++) acc[m][n] = (f32x4){0.f, 0.f, 0.f, 0.f};

  bf16x8* dA = lds;
  bf16x8* dB = lds + 1024;
  // prologue: stage tile 0
#pragma unroll
  for (int q = 0; q < 4; q++) {
    gl16(pA[q], dA + q * 256 + w * 64);
    gl16(pB[q], dB + q * 256 + w * 64);
  }

  const int NK = I_DIM / 64;  // 32
  for (int kt = 0; kt < NK; ++kt) {
    __syncthreads();           // drain
#pragma unroll
    for (int ks = 0; ks < 2; ks++) {
      bf16x8 af[4], bfr[4];
#pragma unroll
      for (int mf = 0; mf < 4; mf++) af[mf] = lds[swzc(wr * 64 + mf * 16 + fr, ks * 4 + fs)];
#pragma unroll
      for (int nf = 0; nf < 4; nf++) bfr[nf] = dB[swzc(wc * 64 + nf * 16 + fr, ks * 4 + fs)];
      __builtin_amdgcn_s_setprio(1);
#pragma unroll
      for (int m = 0; m < 4; m++)
#pragma unroll
        for (int n = 0; n < 4; n++)
          acc[m][n] = __builtin_amdgcn_mfma_f32_16x16x32_bf16(af[m], bfr[n], acc[m][n], 0, 0, 0);
      __builtin_amdgcn_s_setprio(0);
    }
    __syncthreads();           // WAR
    if (kt + 1 < NK) {
      int ko = (kt + 1) * 8;
#pragma unroll
      for (int q = 0; q < 4; q++) {
        gl16(pA[q] + ko, dA + q * 256 + w * 64);
        gl16(pB[q] + ko, dB + q * 256 + w * 64);
      }
    }
  }

#pragma unroll
  for (int m = 0; m < 4; m++)
#pragma unroll
    for (int n = 0; n < 4; n++)
#pragma unroll
      for (int q2 = 0; q2 < 4; q2++) {
        int row = wr * 64 + m * 16 + fs * 4 + q2;
        int col = n0 + wc * 64 + n * 16 + fr;
        float v = acc[m][n][q2];
        int grow = m0 + row;
        if (sh) out[(size_t)grow * H_DIM + col] = v;
        else if (grow < count) y[(size_t)(base + grow) * H_DIM + col] = (__bf16)v;
      }
}

__global__ __launch_bounds__(256) void k_combine(
    const __bf16* __restrict__ y, const int* __restrict__ counts,
    const int* __restrict__ tE, const int* __restrict__ tP,
    const float* __restrict__ tG, float* __restrict__ out) {
  int t = blockIdx.x;
  int c = threadIdx.x;  // H/4 = 256 quads per token row
  int bases[NE];
  int s = 0;
#pragma unroll
  for (int e = 0; e < NE; e++) { bases[e] = s; s += counts[e]; }
  int e0 = tE[t * 2], e1 = tE[t * 2 + 1];
  int r0 = bases[e0] + tP[t * 2], r1 = bases[e1] + tP[t * 2 + 1];
  float g0 = tG[t * 2], g1 = tG[t * 2 + 1];
  const bf16x4* y4 = (const bf16x4*)y;
  float4* o4 = (float4*)out;
  float4 sv = o4[(size_t)t * (H_DIM / 4) + c];
  bf16x4 a = y4[(size_t)r0 * (H_DIM / 4) + c];
  bf16x4 b = y4[(size_t)r1 * (H_DIM / 4) + c];
  sv.x += g0 * (float)a[0] + g1 * (float)b[0];
  sv.y += g0 * (float)a[1] + g1 * (float)b[1];
  sv.z += g0 * (float)a[2] + g1 * (float)b[2];
  sv.w += g0 * (float)a[3] + g1 * (float)b[3];
  o4[(size_t)t * (H_DIM / 4) + c] = sv;
}

extern "C" void kernel_launch(void* const* d_in, const int* in_sizes, int n_in,
                              void* d_out, int out_size, void* d_ws, size_t ws_size,
                              hipStream_t stream) {
  const float* x = (const float*)d_in[0];
  const float* sg_w = (const float*)d_in[1];
  const float* su_w = (const float*)d_in[2];
  const float* sd_w = (const float*)d_in[3];
  const float* router_w = (const float*)d_in[4];
  const float* routing_bias = (const float*)d_in[5];
  const float* wg = (const float*)d_in[6];
  const float* wu = (const float*)d_in[7];
  const float* wd = (const float*)d_in[8];
  float* out = (float*)d_out;
  char* ws = (char*)d_ws;

  __bf16* xb  = (__bf16*)(ws + 0);            //  8,388,608
  __bf16* hs  = (__bf16*)(ws + 8388608);      // 16,777,216
  __bf16* hr  = (__bf16*)(ws + 25165824);     // 33,554,432
  __bf16* y   = (__bf16*)(ws + 58720256);     // 16,777,216 (bf16)
  __bf16* wgb = (__bf16*)(ws + 92274688);     // 33,554,432
  __bf16* wub = (__bf16*)(ws + 125829120);    // 33,554,432
  __bf16* wdb = (__bf16*)(ws + 159383552);    // 33,554,432
  __bf16* sgb = (__bf16*)(ws + 192937984);    //  4,194,304
  __bf16* sub = (__bf16*)(ws + 197132288);    //  4,194,304
  __bf16* sdb = (__bf16*)(ws + 201326592);    //  4,194,304
  int* counts = (int*)(ws + 205520896);
  int* list   = (int*)(ws + 205520960);       // 131,072
  int* tE     = (int*)(ws + 205652032);       // 32,768
  int* tP     = (int*)(ws + 205684800);       // 32,768
  float* tG   = (float*)(ws + 205717568);     // 32,768

  // prep: wg/wu/sg/su cast (cached) + router scoring (no atomics)
  k_prep<<<NBW + NBS + NT / 4, 256, 0, stream>>>(
      wg, wu, sg_w, su_w, wgb, wub, sgb, sub,
      x, router_w, routing_bias, xb, tE, tG);
  // slot assignment via LDS histogram (writes counts/list/tP)
  k_sched<<<1, 1024, 0, stream>>>(tE, counts, list, tP);
  // upgate GEMM (z<9) + wd/sd cast riding along (z in [9,18))
  dim3 gu(I_DIM / 64, NT / 128, (NE + 1) + 9);
  k_upgate97<<<gu, 256, 0, stream>>>(xb, wgb, wub, sgb, sub, counts, list,
                                     hs, hr, wd, sd_w, wdb, sdb);
  dim3 gd(H_DIM / 128, NT / 128, NE + 1);
  k_down97<<<gd, 256, 0, stream>>>(hs, hr, wdb, sdb, counts, out, y);
  k_combine<<<NT, 256, 0, stream>>>(y, counts, tE, tP, tG, out);
}

// Round 17
// 264.831 us; speedup vs baseline: 1.1276x; 1.0022x over previous
//
#include <hip/hip_runtime.h>
#include <hip/hip_bf16.h>

#define H_DIM 1024
#define I_DIM 2048
#define NE 8
#define NT 4096

typedef __bf16 bf16x8 __attribute__((ext_vector_type(8)));
typedef __bf16 bf16x4 __attribute__((ext_vector_type(4)));
typedef float f32x4 __attribute__((ext_vector_type(4)));

// 16B-chunk index within a [rows][8-chunk] LDS tile, XOR-swizzled (verified
// conflict-free R1-R16: SQ_LDS_BANK_CONFLICT == 0).
__device__ __forceinline__ int swzc(int r, int j) { return r * 8 + (j ^ (r & 7)); }

// async global->LDS, 16B per lane. LDS dest is wave-uniform base (HW adds lane*16).
__device__ __forceinline__ void gl16(const void* g, void* l) {
  __builtin_amdgcn_global_load_lds(
      (const __attribute__((address_space(1))) unsigned int*)g,
      (__attribute__((address_space(3))) unsigned int*)l, 16, 0, 0);
}

__device__ __forceinline__ bf16x8 cvt8(float4 a, float4 b) {
  bf16x8 r;
  r[0] = (__bf16)a.x; r[1] = (__bf16)a.y; r[2] = (__bf16)a.z; r[3] = (__bf16)a.w;
  r[4] = (__bf16)b.x; r[5] = (__bf16)b.y; r[6] = (__bf16)b.z; r[7] = (__bf16)b.w;
  return r;
}

// plain cached fp32->bf16 chunk cast (nt variant regressed in R14)
__device__ __forceinline__ void castchunk(const float* s, __bf16* d, int off) {
  const float4* s4 = (const float4*)s;
  float4 a = s4[(size_t)off * 2], b = s4[(size_t)off * 2 + 1];
  ((bf16x8*)d)[off] = cvt8(a, b);
}

// wg/wu cast split: prep does chunks [0, 3M), sched-launch does the rest.
#define NBW_PREP 12288   // 12288*256 = 3,145,728 chunks of wg+wu
#define NBW_SCHED 4096   // 4096*256 = 1,048,576 chunks (tail of wg+wu)
#define NBS 2048         // sg+su: 2*2^18 chunks / 256

// Prep: cast first 3M wg/wu chunks + router SCORING ONLY (no atomics).
__global__ __launch_bounds__(256) void k_prep(
    const float* __restrict__ wg, const float* __restrict__ wu,
    __bf16* __restrict__ wgb, __bf16* __restrict__ wub,
    const float* __restrict__ x, const float* __restrict__ rw,
    const float* __restrict__ rbias, __bf16* __restrict__ xb,
    int* __restrict__ tE, float* __restrict__ tG) {
  if (blockIdx.x < NBW_PREP) {
    int i = blockIdx.x * 256 + threadIdx.x;
    if (i < (1 << 21)) castchunk(wg, wgb, i);
    else castchunk(wu, wub, i - (1 << 21));
    return;
  }
  // ---- router scoring (sigmoid top-2 renorm; fuses x->bf16; NO atomics) ----
  int blk = blockIdx.x - NBW_PREP;            // 0..1023
  int wv = threadIdx.x >> 6, lane = threadIdx.x & 63;
  int t = blk * 4 + wv;
  float acc[NE];
#pragma unroll
  for (int e = 0; e < NE; e++) acc[e] = 0.f;
  const float4* xr = (const float4*)(x + (size_t)t * H_DIM);
  const float4* wr4 = (const float4*)rw;
  bf16x4* xo = (bf16x4*)xb + (size_t)t * (H_DIM / 4);
#pragma unroll
  for (int it = 0; it < 4; ++it) {
    int c = it * 64 + lane;
    float4 xv = xr[c];
    bf16x4 bv;
    bv[0] = (__bf16)xv.x; bv[1] = (__bf16)xv.y;
    bv[2] = (__bf16)xv.z; bv[3] = (__bf16)xv.w;
    xo[c] = bv;
#pragma unroll
    for (int e = 0; e < NE; e++) {
      float4 wv2 = wr4[e * (H_DIM / 4) + c];
      acc[e] += xv.x * wv2.x + xv.y * wv2.y + xv.z * wv2.z + xv.w * wv2.w;
    }
  }
#pragma unroll
  for (int e = 0; e < NE; e++) {
#pragma unroll
    for (int off = 32; off > 0; off >>= 1) acc[e] += __shfl_xor(acc[e], off, 64);
  }
  if (lane == 0) {
    float p[NE];
#pragma unroll
    for (int e = 0; e < NE; e++) p[e] = 1.f / (1.f + expf(-(acc[e] + rbias[e])));
    int e0 = 0;
#pragma unroll
    for (int e = 1; e < NE; e++) if (p[e] > p[e0]) e0 = e;
    int e1 = -1;
#pragma unroll
    for (int e = 0; e < NE; e++) if (e != e0 && (e1 < 0 || p[e] > p[e1])) e1 = e;
    float s = p[e0] + p[e1];
    tE[t * 2] = e0; tE[t * 2 + 1] = e1;
    tG[t * 2] = p[e0] / s; tG[t * 2 + 1] = p[e1] / s;
  }
}

// Sched launch: block 0 = LDS-histogram slot assignment; blocks [1, 1+6144)
// = cast of wg/wu tail + sg/su (fills the otherwise-idle GPU during sched).
__global__ __launch_bounds__(256) void k_sched(
    const int* __restrict__ tE, int* __restrict__ counts,
    int* __restrict__ list, int* __restrict__ tP,
    const float* __restrict__ wg, const float* __restrict__ wu,
    const float* __restrict__ sg, const float* __restrict__ su,
    __bf16* __restrict__ wgb, __bf16* __restrict__ wub,
    __bf16* __restrict__ sgb, __bf16* __restrict__ sub) {
  if (blockIdx.x > 0) {
    int b = blockIdx.x - 1;
    if (b < NBW_SCHED) {
      int i = NBW_PREP * 256 + b * 256 + threadIdx.x;  // tail of wg+wu
      if (i < (1 << 21)) castchunk(wg, wgb, i);
      else castchunk(wu, wub, i - (1 << 21));
    } else {
      int i = (b - NBW_SCHED) * 256 + threadIdx.x;
      if (i < (1 << 18)) castchunk(sg, sgb, i);
      else castchunk(su, sub, i - (1 << 18));
    }
    return;
  }
  __shared__ int lc[NE];
  int tid = threadIdx.x;
  if (tid < NE) lc[tid] = 0;
  __syncthreads();
  for (int t = tid; t < NT; t += 256) {
    int e0 = tE[t * 2], e1 = tE[t * 2 + 1];
    int p0 = atomicAdd(&lc[e0], 1);
    list[e0 * NT + p0] = t;
    tP[t * 2] = p0;
    int p1 = atomicAdd(&lc[e1], 1);
    list[e1 * NT + p1] = t;
    tP[t * 2 + 1] = p1;
  }
  __syncthreads();
  if (tid < NE) counts[tid] = lc[tid];
}

// ---------------------------------------------------------------------------
// Fused gate+up GEMM, m97 form: 128 rows x 64 i-cols x {g,u}, BK=64, 4 waves,
// SINGLE 32 KB LDS -> 4 blocks/CU (R16 win). Grid z: z<9 GEMM, z>=9 wd/sd
// cast riding along (down consumes wdb/sdb only in the next launch).
// ---------------------------------------------------------------------------
__global__ __launch_bounds__(256, 4) void k_upgate97(
    const __bf16* __restrict__ xb, const __bf16* __restrict__ wgb,
    const __bf16* __restrict__ wub, const __bf16* __restrict__ sgb,
    const __bf16* __restrict__ sub, const int* __restrict__ counts,
    const int* __restrict__ list,
    __bf16* __restrict__ hs, __bf16* __restrict__ hr,
    const float* __restrict__ wd, const float* __restrict__ sdw,
    __bf16* __restrict__ wdb, __bf16* __restrict__ sdb) {
  int z = blockIdx.z;
  if (z >= NE + 1) {
    // ---- wd/sd cast: (z-9) in [0,9) -> 9216 blocks, 1 chunk/thread ----
    int id = (((z - (NE + 1)) * 32 + blockIdx.y) * 32 + blockIdx.x) * 256 + threadIdx.x;
    if (id < (1 << 21)) castchunk(wd, wdb, id);
    else castchunk(sdw, sdb, id - (1 << 21));
    return;
  }
  int m0 = blockIdx.y * 128, n0 = blockIdx.x * 64;
  bool sh = (z == NE);
  int count, base = 0;
  const __bf16 *Bg, *Bu;
  if (sh) {
    count = NT; Bg = sgb; Bu = sub;
  } else {
    count = counts[z];
    if (m0 >= count) return;
    for (int e = 0; e < z; e++) base += counts[e];
    Bg = wgb + (size_t)z * (I_DIM * H_DIM);
    Bu = wub + (size_t)z * (I_DIM * H_DIM);
  }

  __shared__ bf16x8 lds[2048];   // [A 1024 | B 1024] = 32 KB single buffer

  int tid = threadIdx.x, lane = tid & 63, w = tid >> 6;
  int wr = w >> 1, wc = w & 1;
  int fr = lane & 15, fs = lane >> 4;

  const bf16x8* a8 = (const bf16x8*)xb;
  const bf16x8* g8 = (const bf16x8*)Bg;
  const bf16x8* u8 = (const bf16x8*)Bu;

  const bf16x8* pA[4];
  const bf16x8* pB[4];
#pragma unroll
  for (int q = 0; q < 4; q++) {
    int c = q * 256 + tid;                  // chunk 0..1023 (128 rows x 8)
    int r = c >> 3, j = (c & 7) ^ (r & 7);
    int gr = m0 + r;
    int tok = sh ? gr : ((gr < count) ? list[z * NT + gr] : list[z * NT]);
    pA[q] = a8 + (size_t)tok * (H_DIM / 8) + j;
    int G = r >> 6, gu = (r >> 5) & 1, cc = r & 31;
    pB[q] = (gu ? u8 : g8) + (size_t)(n0 + G * 32 + cc) * (H_DIM / 8) + j;
  }

  f32x4 acc[4][4];
#pragma unroll
  for (int m = 0; m < 4; m++)
#pragma unroll
    for (int n = 0; n < 4; n++) acc[m][n] = (f32x4){0.f, 0.f, 0.f, 0.f};

  bf16x8* dA = lds;
  bf16x8* dB = lds + 1024;
#pragma unroll
  for (int q = 0; q < 4; q++) {
    gl16(pA[q], dA + q * 256 + w * 64);
    gl16(pB[q], dB + q * 256 + w * 64);
  }

  const int NK = H_DIM / 64;  // 16
  for (int kt = 0; kt < NK; ++kt) {
    __syncthreads();           // drain: tile kt landed
#pragma unroll
    for (int ks = 0; ks < 2; ks++) {
      bf16x8 af[4], bfr[4];
#pragma unroll
      for (int mf = 0; mf < 4; mf++) af[mf] = lds[swzc(wr * 64 + mf * 16 + fr, ks * 4 + fs)];
#pragma unroll
      for (int nf = 0; nf < 4; nf++) bfr[nf] = dB[swzc(wc * 64 + nf * 16 + fr, ks * 4 + fs)];
      __builtin_amdgcn_s_setprio(1);
#pragma unroll
      for (int m = 0; m < 4; m++)
#pragma unroll
        for (int n = 0; n < 4; n++)
          acc[m][n] = __builtin_amdgcn_mfma_f32_16x16x32_bf16(af[m], bfr[n], acc[m][n], 0, 0, 0);
      __builtin_amdgcn_s_setprio(0);
    }
    __syncthreads();           // WAR: all waves done reading before restage
    if (kt + 1 < NK) {
      int ko = (kt + 1) * 8;
#pragma unroll
      for (int q = 0; q < 4; q++) {
        gl16(pA[q] + ko, dA + q * 256 + w * 64);
        gl16(pB[q] + ko, dB + q * 256 + w * 64);
      }
    }
  }

  // epilogue: h = silu(g)*u; g = acc[m][np], u = acc[m][np+2]
#pragma unroll
  for (int m = 0; m < 4; m++)
#pragma unroll
    for (int np = 0; np < 2; np++)
#pragma unroll
      for (int q2 = 0; q2 < 4; q2++) {
        int row = wr * 64 + m * 16 + fs * 4 + q2;
        int col = n0 + wc * 32 + np * 16 + fr;
        float g = acc[m][np][q2], u = acc[m][np + 2][q2];
        float h = g * u / (1.f + expf(-g));
        __bf16 hb = (__bf16)h;
        int grow = m0 + row;
        if (sh) hs[(size_t)grow * I_DIM + col] = hb;
        else if (grow < count) hr[(size_t)(base + grow) * I_DIM + col] = hb;
      }
}

// ---------------------------------------------------------------------------
// Down GEMM, m97 form: 128x128, BK=64, 4 waves, single 32 KB LDS ->
// 4 blocks/CU. Routed output y bf16.
// ---------------------------------------------------------------------------
__global__ __launch_bounds__(256, 4) void k_down97(
    const __bf16* __restrict__ hs, const __bf16* __restrict__ hr,
    const __bf16* __restrict__ wdb, const __bf16* __restrict__ sdb,
    const int* __restrict__ counts,
    float* __restrict__ out, __bf16* __restrict__ y) {
  int z = blockIdx.z;
  int m0 = blockIdx.y * 128, n0 = blockIdx.x * 128;
  bool sh = (z == NE);
  int count, base = 0;
  const __bf16 *B, *A;
  if (sh) {
    count = NT; B = sdb; A = hs;
  } else {
    count = counts[z];
    if (m0 >= count) return;
    for (int e = 0; e < z; e++) base += counts[e];
    B = wdb + (size_t)z * (H_DIM * I_DIM);
    A = hr + (size_t)base * I_DIM;
  }

  __shared__ bf16x8 lds[2048];   // 32 KB single buffer

  int tid = threadIdx.x, lane = tid & 63, w = tid >> 6;
  int wr = w >> 1, wc = w & 1;
  int fr = lane & 15, fs = lane >> 4;

  const bf16x8* a8 = (const bf16x8*)A;
  const bf16x8* b8 = (const bf16x8*)B;

  const bf16x8* pA[4];
  const bf16x8* pB[4];
#pragma unroll
  for (int q = 0; q < 4; q++) {
    int c = q * 256 + tid;
    int r = c >> 3, j = (c & 7) ^ (r & 7);
    int ra = m0 + r; if (ra >= count) ra = count - 1;
    pA[q] = a8 + (size_t)ra * (I_DIM / 8) + j;
    pB[q] = b8 + (size_t)(n0 + r) * (I_DIM / 8) + j;
  }

  f32x4 acc[4][4];
#pragma unroll
  for (int m = 0; m < 4; m++)
#pragma unroll
    for (int n = 0; n < 4; n++) acc[m][n] = (f32x4){0.f, 0.f, 0.f, 0.f};

  bf16x8* dA = lds;
  bf16x8* dB = lds + 1024;
#pragma unroll
  for (int q = 0; q < 4; q++) {
    gl16(pA[q], dA + q * 256 + w * 64);
    gl16(pB[q], dB + q * 256 + w * 64);
  }

  const int NK = I_DIM / 64;  // 32
  for (int kt = 0; kt < NK; ++kt) {
    __syncthreads();           // drain
#pragma unroll
    for (int ks = 0; ks < 2; ks++) {
      bf16x8 af[4], bfr[4];
#pragma unroll
      for (int mf = 0; mf < 4; mf++) af[mf] = lds[swzc(wr * 64 + mf * 16 + fr, ks * 4 + fs)];
#pragma unroll
      for (int nf = 0; nf < 4; nf++) bfr[nf] = dB[swzc(wc * 64 + nf * 16 + fr, ks * 4 + fs)];
      __builtin_amdgcn_s_setprio(1);
#pragma unroll
      for (int m = 0; m < 4; m++)
#pragma unroll
        for (int n = 0; n < 4; n++)
          acc[m][n] = __builtin_amdgcn_mfma_f32_16x16x32_bf16(af[m], bfr[n], acc[m][n], 0, 0, 0);
      __builtin_amdgcn_s_setprio(0);
    }
    __syncthreads();           // WAR
    if (kt + 1 < NK) {
      int ko = (kt + 1) * 8;
#pragma unroll
      for (int q = 0; q < 4; q++) {
        gl16(pA[q] + ko, dA + q * 256 + w * 64);
        gl16(pB[q] + ko, dB + q * 256 + w * 64);
      }
    }
  }

#pragma unroll
  for (int m = 0; m < 4; m++)
#pragma unroll
    for (int n = 0; n < 4; n++)
#pragma unroll
      for (int q2 = 0; q2 < 4; q2++) {
        int row = wr * 64 + m * 16 + fs * 4 + q2;
        int col = n0 + wc * 64 + n * 16 + fr;
        float v = acc[m][n][q2];
        int grow = m0 + row;
        if (sh) out[(size_t)grow * H_DIM + col] = v;
        else if (grow < count) y[(size_t)(base + grow) * H_DIM + col] = (__bf16)v;
      }
}

__global__ __launch_bounds__(256) void k_combine(
    const __bf16* __restrict__ y, const int* __restrict__ counts,
    const int* __restrict__ tE, const int* __restrict__ tP,
    const float* __restrict__ tG, float* __restrict__ out) {
  int t = blockIdx.x;
  int c = threadIdx.x;  // H/4 = 256 quads per token row
  int bases[NE];
  int s = 0;
#pragma unroll
  for (int e = 0; e < NE; e++) { bases[e] = s; s += counts[e]; }
  int e0 = tE[t * 2], e1 = tE[t * 2 + 1];
  int r0 = bases[e0] + tP[t * 2], r1 = bases[e1] + tP[t * 2 + 1];
  float g0 = tG[t * 2], g1 = tG[t * 2 + 1];
  const bf16x4* y4 = (const bf16x4*)y;
  float4* o4 = (float4*)out;
  float4 sv = o4[(size_t)t * (H_DIM / 4) + c];
  bf16x4 a = y4[(size_t)r0 * (H_DIM / 4) + c];
  bf16x4 b = y4[(size_t)r1 * (H_DIM / 4) + c];
  sv.x += g0 * (float)a[0] + g1 * (float)b[0];
  sv.y += g0 * (float)a[1] + g1 * (float)b[1];
  sv.z += g0 * (float)a[2] + g1 * (float)b[2];
  sv.w += g0 * (float)a[3] + g1 * (float)b[3];
  o4[(size_t)t * (H_DIM / 4) + c] = sv;
}

extern "C" void kernel_launch(void* const* d_in, const int* in_sizes, int n_in,
                              void* d_out, int out_size, void* d_ws, size_t ws_size,
                              hipStream_t stream) {
  const float* x = (const float*)d_in[0];
  const float* sg_w = (const float*)d_in[1];
  const float* su_w = (const float*)d_in[2];
  const float* sd_w = (const float*)d_in[3];
  const float* router_w = (const float*)d_in[4];
  const float* routing_bias = (const float*)d_in[5];
  const float* wg = (const float*)d_in[6];
  const float* wu = (const float*)d_in[7];
  const float* wd = (const float*)d_in[8];
  float* out = (float*)d_out;
  char* ws = (char*)d_ws;

  __bf16* xb  = (__bf16*)(ws + 0);            //  8,388,608
  __bf16* hs  = (__bf16*)(ws + 8388608);      // 16,777,216
  __bf16* hr  = (__bf16*)(ws + 25165824);     // 33,554,432
  __bf16* y   = (__bf16*)(ws + 58720256);     // 16,777,216 (bf16)
  __bf16* wgb = (__bf16*)(ws + 92274688);     // 33,554,432
  __bf16* wub = (__bf16*)(ws + 125829120);    // 33,554,432
  __bf16* wdb = (__bf16*)(ws + 159383552);    // 33,554,432
  __bf16* sgb = (__bf16*)(ws + 192937984);    //  4,194,304
  __bf16* sub = (__bf16*)(ws + 197132288);    //  4,194,304
  __bf16* sdb = (__bf16*)(ws + 201326592);    //  4,194,304
  int* counts = (int*)(ws + 205520896);
  int* list   = (int*)(ws + 205520960);       // 131,072
  int* tE     = (int*)(ws + 205652032);       // 32,768
  int* tP     = (int*)(ws + 205684800);       // 32,768
  float* tG   = (float*)(ws + 205717568);     // 32,768

  // prep: first 3M wg/wu chunks + router scoring (no atomics)
  k_prep<<<NBW_PREP + NT / 4, 256, 0, stream>>>(
      wg, wu, wgb, wub, x, router_w, routing_bias, xb, tE, tG);
  // sched launch: histogram (block 0) + wg/wu tail + sg/su cast (fills idle GPU)
  k_sched<<<1 + NBW_SCHED + NBS, 256, 0, stream>>>(
      tE, counts, list, tP, wg, wu, sg_w, su_w, wgb, wub, sgb, sub);
  // upgate GEMM (z<9) + wd/sd cast riding along (z in [9,18))
  dim3 gu(I_DIM / 64, NT / 128, (NE + 1) + 9);
  k_upgate97<<<gu, 256, 0, stream>>>(xb, wgb, wub, sgb, sub, counts, list,
                                     hs, hr, wd, sd_w, wdb, sdb);
  dim3 gd(H_DIM / 128, NT / 128, NE + 1);
  k_down97<<<gd, 256, 0, stream>>>(hs, hr, wdb, sdb, counts, out, y);
  k_combine<<<NT, 256, 0, stream>>>(y, counts, tE, tP, tG, out);
}